// Round 6
// baseline (173.219 us; speedup 1.0000x reference)
//
#include <hip/hip_runtime.h>

#define EPSB 1e-3f

typedef _Float16 half8 __attribute__((ext_vector_type(8)));
typedef _Float16 half4 __attribute__((ext_vector_type(4)));
typedef float f32x4 __attribute__((ext_vector_type(4)));

// ---------------- prep: weights -> MFMA-fragment order (f16), BN fold ----------------
// WF layout: frag (s, ct) is 1 KB: WF[((s*4+ct)*64 + lane)*8 + k]
// A-operand mapping (16x16x32): m = lane&15 -> co = ct*16 + (lane&15)
//                               k = (lane>>4)*8 + j -> K index
__global__ __launch_bounds__(256, 4)
void k_prep(const float* __restrict__ W1, const float* __restrict__ W2,
            const float* __restrict__ b1, const float* __restrict__ g1,
            const float* __restrict__ be1, const float* __restrict__ mu1,
            const float* __restrict__ v1,
            const float* __restrict__ b2, const float* __restrict__ g2,
            const float* __restrict__ be2, const float* __restrict__ mu2,
            const float* __restrict__ v2,
            _Float16* __restrict__ W1F, _Float16* __restrict__ W2F,
            float* __restrict__ ST)
{
    int t = blockIdx.x * 256 + threadIdx.x;
    if (t < 5 * 4 * 64 * 8) {                 // W1F
        int k = t & 7, lane = (t >> 3) & 63, snt = t >> 9;
        int s = snt >> 2, ct = snt & 3;
        int quad = lane >> 4, n16 = lane & 15;
        int tap = 2 * s + (quad >> 1);
        int ci  = (quad & 1) * 8 + k;
        int co  = ct * 16 + n16;
        float v = (tap < 9) ? W1[(tap * 16 + ci) * 64 + co] : 0.f;
        W1F[t] = (_Float16)v;
        return;
    }
    t -= 5 * 4 * 64 * 8;
    if (t < 18 * 4 * 64 * 8) {                // W2F
        int k = t & 7, lane = (t >> 3) & 63, snt = t >> 9;
        int s = snt >> 2, ct = snt & 3;
        int quad = lane >> 4, n16 = lane & 15;
        int tap = s >> 1;
        int ci  = (s & 1) * 32 + quad * 8 + k;
        int co  = ct * 16 + n16;
        W2F[t] = (_Float16)W2[(tap * 64 + ci) * 64 + co];
        return;
    }
    t -= 18 * 4 * 64 * 8;
    if (t < 256) {
        int c = t & 63, sel = t >> 6;
        if (sel == 0)      ST[c]       = g1[c] * rsqrtf(v1[c] + EPSB);
        else if (sel == 1) ST[64 + c]  = (b1[c] - mu1[c]) * (g1[c] * rsqrtf(v1[c] + EPSB)) + be1[c];
        else if (sel == 2) ST[128 + c] = g2[c] * rsqrtf(v2[c] + EPSB);
        else               ST[192 + c] = (b2[c] - mu2[c]) * (g2[c] * rsqrtf(v2[c] + EPSB)) + be2[c];
    }
}

// ---------------- conv1: 16->64, MFMA, 4r x 64q tile (qt=4), coalesced f16 out ----------------
#define CIP1 24   // padded pixel stride in f16 (48 B) for input stage
__global__ __launch_bounds__(256, 3)
void k_conv1(const float* __restrict__ mr, const _Float16* __restrict__ W1F,
             const float* __restrict__ ST, _Float16* __restrict__ A)
{
    __shared__ __align__(16) _Float16 sM[4 * 64 * 72];   // 36,864 B (input stage uses 6*66*24=9504)
    const int tid = threadIdx.x;
    const int b  = blockIdx.y;
    const int r0 = (blockIdx.x >> 2) * 4;
    const int q0 = (blockIdx.x & 3) * 64;

    for (int idx = tid; idx < 6 * 66 * 2; idx += 256) {
        int c = idx & 1, pp = idx >> 1;
        int p = pp % 66, dy = pp / 66;
        int rr = r0 + dy - 1, qg = q0 + p - 1;
        half8 h = (half8)(_Float16)0.f;
        if ((unsigned)rr < 256u && (unsigned)qg < 256u) {
            const float* src = mr + ((b * 256 + rr) * 256 + qg) * 16 + c * 8;
            float4 v0 = *(const float4*)src;
            float4 v1 = *(const float4*)(src + 4);
            h = (half8){(_Float16)v0.x, (_Float16)v0.y, (_Float16)v0.z, (_Float16)v0.w,
                        (_Float16)v1.x, (_Float16)v1.y, (_Float16)v1.z, (_Float16)v1.w};
        }
        *(half8*)(&sM[(dy * 66 + p) * CIP1 + c * 8]) = h;
    }
    __syncthreads();

    const int w = tid >> 6, lane = tid & 63;     // wave w = row w
    const int n16 = lane & 15, quad = lane >> 4;
    const int ci0 = (quad & 1) * 8;

    f32x4 acc[4][4];   // [qt][ct]
    #pragma unroll
    for (int i = 0; i < 4; ++i)
        #pragma unroll
        for (int j = 0; j < 4; ++j) acc[i][j] = (f32x4){0.f, 0.f, 0.f, 0.f};

    #pragma unroll
    for (int s = 0; s < 5; ++s) {
        int tap  = 2 * s + (quad >> 1);
        int tapc = tap > 8 ? 8 : tap;
        int dy = tapc / 3, dx = tapc % 3;
        half8 wfrag[4], pfrag[4];
        #pragma unroll
        for (int ct = 0; ct < 4; ++ct)
            wfrag[ct] = *(const half8*)(W1F + ((s * 4 + ct) * 64 + lane) * 8);
        #pragma unroll
        for (int qt = 0; qt < 4; ++qt)
            pfrag[qt] = *(const half8*)&sM[((w + dy) * 66 + qt * 16 + n16 + dx) * CIP1 + ci0];
        #pragma unroll
        for (int qt = 0; qt < 4; ++qt)
            #pragma unroll
            for (int ct = 0; ct < 4; ++ct)
                acc[qt][ct] = __builtin_amdgcn_mfma_f32_16x16x32_f16(wfrag[ct], pfrag[qt], acc[qt][ct], 0, 0, 0);
    }

    // BN + ReLU -> registers
    half4 hv[4][4];    // [ct][qt]
    #pragma unroll
    for (int ct = 0; ct < 4; ++ct) {
        int co0 = ct * 16 + quad * 4;
        f32x4 sc = *(const f32x4*)&ST[co0];
        f32x4 sh = *(const f32x4*)&ST[64 + co0];
        #pragma unroll
        for (int qt = 0; qt < 4; ++qt) {
            half4 h;
            #pragma unroll
            for (int j = 0; j < 4; ++j)
                h[j] = (_Float16)fmaxf(acc[qt][ct][j] * sc[j] + sh[j], 0.f);
            hv[ct][qt] = h;
        }
    }
    __syncthreads();
    #pragma unroll
    for (int ct = 0; ct < 4; ++ct) {
        int co0 = ct * 16 + quad * 4;
        #pragma unroll
        for (int qt = 0; qt < 4; ++qt) {
            int ql = qt * 16 + n16;
            *(half4*)(&sM[(w * 64 + ql) * 72 + co0]) = hv[ct][qt];
        }
    }
    __syncthreads();

    // coalesced A store: 4 rows x 64 q x 64 ch f16 = 2048 int4
    for (int idx = tid; idx < 2048; idx += 256) {
        int rl2 = idx >> 9, rest = idx & 511;
        int ql = rest >> 3, seg = rest & 7;
        int4 v = *(const int4*)&sM[(rl2 * 64 + ql) * 72 + seg * 8];
        *(int4*)(A + (((b * 256 + r0 + rl2) * 256 + q0 + ql) * 64 + seg * 8)) = v;
    }
}

// ------- conv2: 64->64 MFMA, 4r x 64q tile (qt=4), BN+softmax+mask + fused s2, coalesced -------
#define CIP2 72   // padded pixel stride in f16 (144 B)
__global__ __launch_bounds__(256, 2)
void k_conv2(const _Float16* __restrict__ A, const _Float16* __restrict__ W2F,
             const float* __restrict__ ST, const float* __restrict__ pet,
             _Float16* __restrict__ BF, float* __restrict__ S2)
{
    __shared__ __align__(16) _Float16 sM[6 * 66 * CIP2];   // 57,024 B; reused for BF tile
    const int tid = threadIdx.x;
    const int b  = blockIdx.y;
    const int r0 = (blockIdx.x >> 2) * 4;
    const int q0 = (blockIdx.x & 3) * 64;

    for (int idx = tid; idx < 6 * 66 * 8; idx += 256) {
        int c = idx & 7, pp = idx >> 3;
        int p = pp % 66, dy = pp / 66;
        int rr = r0 + dy - 1, qg = q0 + p - 1;
        int4 v = {0, 0, 0, 0};
        if ((unsigned)rr < 256u && (unsigned)qg < 256u)
            v = *(const int4*)(A + (((b * 256 + rr) * 256 + qg) * 64 + c * 8));
        *(int4*)(&sM[(dy * 66 + p) * CIP2 + c * 8]) = v;
    }
    __syncthreads();

    const int w = tid >> 6, lane = tid & 63;    // wave w = row w
    const int n16 = lane & 15, quad = lane >> 4;

    f32x4 acc[4][4];   // [qt][ct]
    #pragma unroll
    for (int i = 0; i < 4; ++i)
        #pragma unroll
        for (int j = 0; j < 4; ++j) acc[i][j] = (f32x4){0.f, 0.f, 0.f, 0.f};

    #pragma unroll
    for (int s = 0; s < 18; ++s) {
        const int tap = s >> 1;
        const int dy = tap / 3, dx = tap % 3;
        const int ci0 = (s & 1) * 32 + quad * 8;
        half8 wfrag[4], pfrag[4];
        #pragma unroll
        for (int ct = 0; ct < 4; ++ct)
            wfrag[ct] = *(const half8*)(W2F + ((s * 4 + ct) * 64 + lane) * 8);
        #pragma unroll
        for (int qt = 0; qt < 4; ++qt)
            pfrag[qt] = *(const half8*)&sM[((w + dy) * 66 + qt * 16 + n16 + dx) * CIP2 + ci0];
        #pragma unroll
        for (int qt = 0; qt < 4; ++qt)
            #pragma unroll
            for (int ct = 0; ct < 4; ++ct)
                acc[qt][ct] = __builtin_amdgcn_mfma_f32_16x16x32_f16(wfrag[ct], pfrag[qt], acc[qt][ct], 0, 0, 0);
    }

    // BN + softmax(4 in-lane) + mask -> registers
    half4 hv[4][4];    // [ct][qt]
    #pragma unroll
    for (int ct = 0; ct < 4; ++ct) {
        int co0 = ct * 16 + quad * 4;
        f32x4 sc = *(const f32x4*)&ST[128 + co0];
        f32x4 sh = *(const f32x4*)&ST[192 + co0];
        #pragma unroll
        for (int qt = 0; qt < 4; ++qt) {
            float z0 = acc[qt][ct][0] * sc[0] + sh[0];
            float z1 = acc[qt][ct][1] * sc[1] + sh[1];
            float z2 = acc[qt][ct][2] * sc[2] + sh[2];
            float z3 = acc[qt][ct][3] * sc[3] + sh[3];
            float mx = fmaxf(fmaxf(z0, z1), fmaxf(z2, z3));
            float e0 = __expf(z0 - mx), e1 = __expf(z1 - mx);
            float e2 = __expf(z2 - mx), e3 = __expf(z3 - mx);
            float inv = __builtin_amdgcn_rcpf((e0 + e1) + (e2 + e3));
            float p0 = e0 * inv, p1 = e1 * inv, p2 = e2 * inv, p3 = e3 * inv;
            half4 h;
            h[0] = (_Float16)(p0 > 1e-5f ? p0 : 0.f);
            h[1] = (_Float16)(p1 > 1e-5f ? p1 : 0.f);
            h[2] = (_Float16)(p2 > 1e-5f ? p2 : 0.f);
            h[3] = (_Float16)(p3 > 1e-5f ? p3 : 0.f);
            hv[ct][qt] = h;
        }
    }
    __syncthreads();   // all pfrag reads done -> safe to overwrite sM
    #pragma unroll
    for (int ct = 0; ct < 4; ++ct) {
        int co0 = ct * 16 + quad * 4;
        #pragma unroll
        for (int qt = 0; qt < 4; ++qt) {
            int ql = qt * 16 + n16;
            *(half4*)(&sM[(w * 64 + ql) * CIP2 + co0]) = hv[ct][qt];
        }
    }
    __syncthreads();

    // coalesced BF store: 4 rows x 64 q x 64 ch f16 = 2048 int4
    for (int idx = tid; idx < 2048; idx += 256) {
        int rl2 = idx >> 9, rest = idx & 511;
        int ql = rest >> 3, seg = rest & 7;
        int4 v = *(const int4*)&sM[(rl2 * 64 + ql) * CIP2 + seg * 8];
        *(int4*)(BF + (((b * 256 + r0 + rl2) * 256 + q0 + ql) * 64 + seg * 8)) = v;
    }

    // fused s2: 2 cell-rows x 32 cells x 8 ch-groups; coalesced 64 B stores
    const int qp = tid >> 3, chg = tid & 7;
    #pragma unroll
    for (int cr = 0; cr < 2; ++cr) {
        float dn[8], kp[8];
        #pragma unroll
        for (int j = 0; j < 8; ++j) { dn[j] = 0.f; kp[j] = 0.f; }
        #pragma unroll
        for (int u = 0; u < 2; ++u)
            #pragma unroll
            for (int v = 0; v < 2; ++v) {
                int rl = 2 * cr + u, ql = 2 * qp + v;
                half8 bf = *(const half8*)(&sM[(rl * 64 + ql) * CIP2 + chg * 8]);
                float2 p2 = *(const float2*)(pet + ((b * 256 + r0 + rl) * 256 + q0 + ql) * 16 + chg * 2);
                #pragma unroll
                for (int j = 0; j < 8; ++j) {
                    float bv = (float)bf[j];
                    dn[j] += bv;
                    kp[j] = fmaf((j < 4) ? p2.x : p2.y, bv, kp[j]);
                }
            }
        float* o = S2 + 2 * ((size_t)(((b * 128 + (r0 >> 1) + cr) * 128 + (q0 >> 1) + qp) * 64) + chg * 8);
        #pragma unroll
        for (int m = 0; m < 4; ++m)
            *(float4*)(o + 4 * m) = make_float4(dn[2*m], kp[2*m], dn[2*m+1], kp[2*m+1]);
    }
}

// ---------------- ratio: 4x4 cells -> 0.25 * kp/dn per patch ----------------
__global__ __launch_bounds__(256, 4)
void k_ratio(const float* __restrict__ S2, float* __restrict__ RATIO)
{
    int t = blockIdx.x * 256 + threadIdx.x;
    int cf = t & 63;
    int j  = (t >> 6) & 63;
    int i  = (t >> 12) & 63;
    int b  = t >> 18;
    float dn = 0.f, kp = 0.f;
    #pragma unroll
    for (int u = 0; u < 4; ++u) {
        int r2 = 2 * i - 1 + u;
        if ((unsigned)r2 >= 128u) continue;
        #pragma unroll
        for (int v = 0; v < 4; ++v) {
            int q2 = 2 * j - 1 + v;
            if ((unsigned)q2 >= 128u) continue;
            float2 s = *(const float2*)(S2 + 2 * (((b * 128 + r2) * 128 + q2) * 64 + cf));
            dn += s.x;
            kp += s.y;
        }
    }
    RATIO[t] = (dn == 0.f) ? 0.f : 0.25f * kp * __builtin_amdgcn_rcpf(dn);
}

// ---------------- out: U-table (i-phase sum) in LDS, dot with bf ----------------
__global__ __launch_bounds__(256, 4)
void k_out(const _Float16* __restrict__ BF, const float* __restrict__ RATIO,
           float* __restrict__ out)
{
    __shared__ __align__(16) float sU[64 * 68];   // [j][cf], row padded to 68
    const int tid = threadIdx.x;
    const int r = blockIdx.x & 255;
    const int b = blockIdx.x >> 8;

    const int i0 = (r <= 253) ? 2 * ((r + 2) >> 3)       : -1;
    const int i1 = (r >= 2)   ? 2 * ((r - 2) >> 3) + 1   : -1;

    for (int idx = tid; idx < 1024; idx += 256) {      // 1024 float4s
        int j = idx >> 4, c4 = idx & 15;
        float4 a = make_float4(0.f, 0.f, 0.f, 0.f);
        if (i0 >= 0) a = *(const float4*)&RATIO[(((b * 64 + i0) * 64 + j) << 6) + 4 * c4];
        float4 bb = make_float4(0.f, 0.f, 0.f, 0.f);
        if (i1 >= 0) bb = *(const float4*)&RATIO[(((b * 64 + i1) * 64 + j) << 6) + 4 * c4];
        *(float4*)&sU[j * 68 + 4 * c4] = make_float4(a.x + bb.x, a.y + bb.y, a.z + bb.z, a.w + bb.w);
    }
    __syncthreads();

    const int q = tid;
    const int j0 = (q <= 253) ? 2 * ((q + 2) >> 3)     : -1;
    const int j1 = (q >= 2)   ? 2 * ((q - 2) >> 3) + 1 : -1;

    const half8* bfp = (const half8*)(BF + ((size_t)(b * 256 + r) * 256 + q) * 64);
    float o[16];
    #pragma unroll
    for (int c = 0; c < 16; ++c) o[c] = 0.f;

    #pragma unroll
    for (int c2 = 0; c2 < 8; ++c2) {
        half8 bf8 = bfp[c2];
        float s0 = 0.f, s1 = 0.f;
        #pragma unroll
        for (int pj = 0; pj < 2; ++pj) {
            int jj = pj ? j1 : j0;
            if (jj < 0) continue;
            const float* up = &sU[jj * 68 + 8 * c2];
            s0 += (float)bf8[0] * up[0] + (float)bf8[1] * up[1]
                + (float)bf8[2] * up[2] + (float)bf8[3] * up[3];
            s1 += (float)bf8[4] * up[4] + (float)bf8[5] * up[5]
                + (float)bf8[6] * up[6] + (float)bf8[7] * up[7];
        }
        o[2 * c2]     = s0;
        o[2 * c2 + 1] = s1;
    }
    float* op = out + ((size_t)(b * 256 + r) * 256 + q) * 16;
    #pragma unroll
    for (int m = 0; m < 4; ++m)
        *(float4*)(op + 4 * m) = make_float4(o[4*m], o[4*m+1], o[4*m+2], o[4*m+3]);
}

extern "C" void kernel_launch(void* const* d_in, const int* in_sizes, int n_in,
                              void* d_out, int out_size, void* d_ws, size_t ws_size,
                              hipStream_t stream) {
    const float* mr  = (const float*)d_in[0];
    const float* pet = (const float*)d_in[1];
    const float* W1  = (const float*)d_in[2];
    const float* b1  = (const float*)d_in[3];
    const float* g1  = (const float*)d_in[4];
    const float* be1 = (const float*)d_in[5];
    const float* mu1 = (const float*)d_in[6];
    const float* v1  = (const float*)d_in[7];
    const float* W2  = (const float*)d_in[8];
    const float* b2  = (const float*)d_in[9];
    const float* g2  = (const float*)d_in[10];
    const float* be2 = (const float*)d_in[11];
    const float* mu2 = (const float*)d_in[12];
    const float* v2  = (const float*)d_in[13];

    // workspace layout (bytes):
    //   [0,        25165824)  A   f16 (3*256*256*64)
    //   [25165824, 50331648)  BF  f16 (3*256*256*64)
    //   [50331648, 75497472)  S2  fp32 (3*128*128*64*2)
    //   [75497472, 78643200)  RATIO fp32 (3*64*64*64)
    //   [78643200, 78663680)  W1F f16
    //   [78663680, 78737408)  W2F f16
    //   [78737408, 78738432)  ST  fp32
    char* ws = (char*)d_ws;
    _Float16* A     = (_Float16*)(ws);
    _Float16* BF    = (_Float16*)(ws + 25165824);
    float*    S2    = (float*)(ws + 50331648);
    float*    RATIO = (float*)(ws + 75497472);
    _Float16* W1F   = (_Float16*)(ws + 78643200);
    _Float16* W2F   = (_Float16*)(ws + 78663680);
    float*    ST    = (float*)(ws + 78737408);
    float*    out   = (float*)d_out;

    dim3 blk(256);
    k_prep<<<185, blk, 0, stream>>>(W1, W2, b1, g1, be1, mu1, v1,
                                    b2, g2, be2, mu2, v2, W1F, W2F, ST);
    k_conv1<<<dim3(256, 3), blk, 0, stream>>>(mr, W1F, ST, A);
    k_conv2<<<dim3(256, 3), blk, 0, stream>>>(A, W2F, ST, pet, BF, S2);
    k_ratio<<<3072, blk, 0, stream>>>(S2, RATIO);
    k_out<<<768, blk, 0, stream>>>(BF, RATIO, out);
}

// Round 7
// 169.277 us; speedup vs baseline: 1.0233x; 1.0233x over previous
//
#include <hip/hip_runtime.h>

#define EPSB 1e-3f

typedef _Float16 half8 __attribute__((ext_vector_type(8)));
typedef _Float16 half4 __attribute__((ext_vector_type(4)));
typedef float f32x4 __attribute__((ext_vector_type(4)));

// ---------------- prep: weights -> MFMA-fragment order (f16), BN fold ----------------
// WF layout: frag (s, ct) is 1 KB: WF[((s*4+ct)*64 + lane)*8 + k]
// A-operand mapping (16x16x32): m = lane&15 -> co = ct*16 + (lane&15)
//                               k = (lane>>4)*8 + j -> K index
__global__ __launch_bounds__(256, 4)
void k_prep(const float* __restrict__ W1, const float* __restrict__ W2,
            const float* __restrict__ b1, const float* __restrict__ g1,
            const float* __restrict__ be1, const float* __restrict__ mu1,
            const float* __restrict__ v1,
            const float* __restrict__ b2, const float* __restrict__ g2,
            const float* __restrict__ be2, const float* __restrict__ mu2,
            const float* __restrict__ v2,
            _Float16* __restrict__ W1F, _Float16* __restrict__ W2F,
            float* __restrict__ ST)
{
    int t = blockIdx.x * 256 + threadIdx.x;
    if (t < 5 * 4 * 64 * 8) {                 // W1F
        int k = t & 7, lane = (t >> 3) & 63, snt = t >> 9;
        int s = snt >> 2, ct = snt & 3;
        int quad = lane >> 4, n16 = lane & 15;
        int tap = 2 * s + (quad >> 1);
        int ci  = (quad & 1) * 8 + k;
        int co  = ct * 16 + n16;
        float v = (tap < 9) ? W1[(tap * 16 + ci) * 64 + co] : 0.f;
        W1F[t] = (_Float16)v;
        return;
    }
    t -= 5 * 4 * 64 * 8;
    if (t < 18 * 4 * 64 * 8) {                // W2F
        int k = t & 7, lane = (t >> 3) & 63, snt = t >> 9;
        int s = snt >> 2, ct = snt & 3;
        int quad = lane >> 4, n16 = lane & 15;
        int tap = s >> 1;
        int ci  = (s & 1) * 32 + quad * 8 + k;
        int co  = ct * 16 + n16;
        W2F[t] = (_Float16)W2[(tap * 64 + ci) * 64 + co];
        return;
    }
    t -= 18 * 4 * 64 * 8;
    if (t < 256) {
        int c = t & 63, sel = t >> 6;
        if (sel == 0)      ST[c]       = g1[c] * rsqrtf(v1[c] + EPSB);
        else if (sel == 1) ST[64 + c]  = (b1[c] - mu1[c]) * (g1[c] * rsqrtf(v1[c] + EPSB)) + be1[c];
        else if (sel == 2) ST[128 + c] = g2[c] * rsqrtf(v2[c] + EPSB);
        else               ST[192 + c] = (b2[c] - mu2[c]) * (g2[c] * rsqrtf(v2[c] + EPSB)) + be2[c];
    }
}

// ---------------- conv1: 16->64, MFMA, 4r x 64q tile, 2-deep pipeline ----------------
#define CIP1 24   // padded pixel stride in f16 (48 B) for input stage
__global__ __launch_bounds__(256, 2)
void k_conv1(const float* __restrict__ mr, const _Float16* __restrict__ W1F,
             const float* __restrict__ ST, _Float16* __restrict__ A)
{
    __shared__ __align__(16) _Float16 sM[4 * 64 * 72];   // 36,864 B (input stage uses 6*66*24=9504)
    const int tid = threadIdx.x;
    const int b  = blockIdx.y;
    const int r0 = (blockIdx.x >> 2) * 4;
    const int q0 = (blockIdx.x & 3) * 64;

    for (int idx = tid; idx < 6 * 66 * 2; idx += 256) {
        int c = idx & 1, pp = idx >> 1;
        int p = pp % 66, dy = pp / 66;
        int rr = r0 + dy - 1, qg = q0 + p - 1;
        half8 h = (half8)(_Float16)0.f;
        if ((unsigned)rr < 256u && (unsigned)qg < 256u) {
            const float* src = mr + ((b * 256 + rr) * 256 + qg) * 16 + c * 8;
            float4 v0 = *(const float4*)src;
            float4 v1 = *(const float4*)(src + 4);
            h = (half8){(_Float16)v0.x, (_Float16)v0.y, (_Float16)v0.z, (_Float16)v0.w,
                        (_Float16)v1.x, (_Float16)v1.y, (_Float16)v1.z, (_Float16)v1.w};
        }
        *(half8*)(&sM[(dy * 66 + p) * CIP1 + c * 8]) = h;
    }
    __syncthreads();

    const int w = tid >> 6, lane = tid & 63;     // wave w = row w
    const int n16 = lane & 15, quad = lane >> 4;
    const int ci0 = (quad & 1) * 8;
    const _Float16* Wl = W1F + lane * 8;

    f32x4 acc[4][4];   // [qt][ct]
    #pragma unroll
    for (int i = 0; i < 4; ++i)
        #pragma unroll
        for (int j = 0; j < 4; ++j) acc[i][j] = (f32x4){0.f, 0.f, 0.f, 0.f};

    // explicit 2-deep rotating pipeline (force ILP / register allocation)
    half8 wf[2][4], pf[2][4];
    auto load_s = [&](int s, int buf) {
        int tap  = 2 * s + (quad >> 1);
        int tapc = tap > 8 ? 8 : tap;
        int dy = tapc / 3, dx = tapc % 3;
        #pragma unroll
        for (int ct = 0; ct < 4; ++ct)
            wf[buf][ct] = *(const half8*)(Wl + (s * 4 + ct) * 512);
        #pragma unroll
        for (int qt = 0; qt < 4; ++qt)
            pf[buf][qt] = *(const half8*)&sM[((w + dy) * 66 + qt * 16 + n16 + dx) * CIP1 + ci0];
    };
    load_s(0, 0);
    load_s(1, 1);
    #pragma unroll
    for (int s = 0; s < 5; ++s) {
        const int buf = s & 1;
        #pragma unroll
        for (int qt = 0; qt < 4; ++qt)
            #pragma unroll
            for (int ct = 0; ct < 4; ++ct)
                acc[qt][ct] = __builtin_amdgcn_mfma_f32_16x16x32_f16(wf[buf][ct], pf[buf][qt], acc[qt][ct], 0, 0, 0);
        if (s + 2 < 5) load_s(s + 2, buf);
    }

    // BN + ReLU -> registers
    half4 hv[4][4];    // [ct][qt]
    #pragma unroll
    for (int ct = 0; ct < 4; ++ct) {
        int co0 = ct * 16 + quad * 4;
        f32x4 sc = *(const f32x4*)&ST[co0];
        f32x4 sh = *(const f32x4*)&ST[64 + co0];
        #pragma unroll
        for (int qt = 0; qt < 4; ++qt) {
            half4 h;
            #pragma unroll
            for (int j = 0; j < 4; ++j)
                h[j] = (_Float16)fmaxf(acc[qt][ct][j] * sc[j] + sh[j], 0.f);
            hv[ct][qt] = h;
        }
    }
    __syncthreads();
    #pragma unroll
    for (int ct = 0; ct < 4; ++ct) {
        int co0 = ct * 16 + quad * 4;
        #pragma unroll
        for (int qt = 0; qt < 4; ++qt) {
            int ql = qt * 16 + n16;
            *(half4*)(&sM[(w * 64 + ql) * 72 + co0]) = hv[ct][qt];
        }
    }
    __syncthreads();

    // coalesced A store: 4 rows x 64 q x 64 ch f16 = 2048 int4
    for (int idx = tid; idx < 2048; idx += 256) {
        int rl2 = idx >> 9, rest = idx & 511;
        int ql = rest >> 3, seg = rest & 7;
        int4 v = *(const int4*)&sM[(rl2 * 64 + ql) * 72 + seg * 8];
        *(int4*)(A + (((b * 256 + r0 + rl2) * 256 + q0 + ql) * 64 + seg * 8)) = v;
    }
}

// ------- conv2: 64->64 MFMA, 4r x 64q tile, 3-deep pipeline, BN+softmax+mask + fused s2 -------
#define CIP2 72   // padded pixel stride in f16 (144 B)
__global__ __launch_bounds__(256, 2)
void k_conv2(const _Float16* __restrict__ A, const _Float16* __restrict__ W2F,
             const float* __restrict__ ST, const float* __restrict__ pet,
             _Float16* __restrict__ BF, float* __restrict__ S2)
{
    __shared__ __align__(16) _Float16 sM[6 * 66 * CIP2];   // 57,024 B; reused for BF tile
    const int tid = threadIdx.x;
    const int b  = blockIdx.y;
    const int r0 = (blockIdx.x >> 2) * 4;
    const int q0 = (blockIdx.x & 3) * 64;

    for (int idx = tid; idx < 6 * 66 * 8; idx += 256) {
        int c = idx & 7, pp = idx >> 3;
        int p = pp % 66, dy = pp / 66;
        int rr = r0 + dy - 1, qg = q0 + p - 1;
        int4 v = {0, 0, 0, 0};
        if ((unsigned)rr < 256u && (unsigned)qg < 256u)
            v = *(const int4*)(A + (((b * 256 + rr) * 256 + qg) * 64 + c * 8));
        *(int4*)(&sM[(dy * 66 + p) * CIP2 + c * 8]) = v;
    }
    __syncthreads();

    const int w = tid >> 6, lane = tid & 63;    // wave w = row w
    const int n16 = lane & 15, quad = lane >> 4;
    const _Float16* Wl = W2F + lane * 8;

    f32x4 acc[4][4];   // [qt][ct]
    #pragma unroll
    for (int i = 0; i < 4; ++i)
        #pragma unroll
        for (int j = 0; j < 4; ++j) acc[i][j] = (f32x4){0.f, 0.f, 0.f, 0.f};

    // explicit 3-deep rotating pipeline (force ILP / register allocation)
    half8 wf[3][4], pf[3][4];
    auto load_s = [&](int s, int buf) {
        const int tap = s >> 1;
        const int dy = tap / 3, dx = tap % 3;
        const int ci0 = (s & 1) * 32 + quad * 8;
        #pragma unroll
        for (int ct = 0; ct < 4; ++ct)
            wf[buf][ct] = *(const half8*)(Wl + (s * 4 + ct) * 512);
        #pragma unroll
        for (int qt = 0; qt < 4; ++qt)
            pf[buf][qt] = *(const half8*)&sM[((w + dy) * 66 + qt * 16 + n16 + dx) * CIP2 + ci0];
    };
    load_s(0, 0);
    load_s(1, 1);
    load_s(2, 2);
    #pragma unroll
    for (int s = 0; s < 18; ++s) {
        const int buf = s % 3;
        #pragma unroll
        for (int qt = 0; qt < 4; ++qt)
            #pragma unroll
            for (int ct = 0; ct < 4; ++ct)
                acc[qt][ct] = __builtin_amdgcn_mfma_f32_16x16x32_f16(wf[buf][ct], pf[buf][qt], acc[qt][ct], 0, 0, 0);
        if (s + 3 < 18) load_s(s + 3, buf);
    }

    // BN + softmax(4 in-lane) + mask -> registers
    half4 hv[4][4];    // [ct][qt]
    #pragma unroll
    for (int ct = 0; ct < 4; ++ct) {
        int co0 = ct * 16 + quad * 4;
        f32x4 sc = *(const f32x4*)&ST[128 + co0];
        f32x4 sh = *(const f32x4*)&ST[192 + co0];
        #pragma unroll
        for (int qt = 0; qt < 4; ++qt) {
            float z0 = acc[qt][ct][0] * sc[0] + sh[0];
            float z1 = acc[qt][ct][1] * sc[1] + sh[1];
            float z2 = acc[qt][ct][2] * sc[2] + sh[2];
            float z3 = acc[qt][ct][3] * sc[3] + sh[3];
            float mx = fmaxf(fmaxf(z0, z1), fmaxf(z2, z3));
            float e0 = __expf(z0 - mx), e1 = __expf(z1 - mx);
            float e2 = __expf(z2 - mx), e3 = __expf(z3 - mx);
            float inv = __builtin_amdgcn_rcpf((e0 + e1) + (e2 + e3));
            float p0 = e0 * inv, p1 = e1 * inv, p2 = e2 * inv, p3 = e3 * inv;
            half4 h;
            h[0] = (_Float16)(p0 > 1e-5f ? p0 : 0.f);
            h[1] = (_Float16)(p1 > 1e-5f ? p1 : 0.f);
            h[2] = (_Float16)(p2 > 1e-5f ? p2 : 0.f);
            h[3] = (_Float16)(p3 > 1e-5f ? p3 : 0.f);
            hv[ct][qt] = h;
        }
    }
    __syncthreads();   // all pfrag reads done -> safe to overwrite sM
    #pragma unroll
    for (int ct = 0; ct < 4; ++ct) {
        int co0 = ct * 16 + quad * 4;
        #pragma unroll
        for (int qt = 0; qt < 4; ++qt) {
            int ql = qt * 16 + n16;
            *(half4*)(&sM[(w * 64 + ql) * CIP2 + co0]) = hv[ct][qt];
        }
    }
    __syncthreads();

    // coalesced BF store: 4 rows x 64 q x 64 ch f16 = 2048 int4
    for (int idx = tid; idx < 2048; idx += 256) {
        int rl2 = idx >> 9, rest = idx & 511;
        int ql = rest >> 3, seg = rest & 7;
        int4 v = *(const int4*)&sM[(rl2 * 64 + ql) * CIP2 + seg * 8];
        *(int4*)(BF + (((b * 256 + r0 + rl2) * 256 + q0 + ql) * 64 + seg * 8)) = v;
    }

    // fused s2: 2 cell-rows x 32 cells x 8 ch-groups; coalesced 64 B stores
    const int qp = tid >> 3, chg = tid & 7;
    #pragma unroll
    for (int cr = 0; cr < 2; ++cr) {
        float dn[8], kp[8];
        #pragma unroll
        for (int j = 0; j < 8; ++j) { dn[j] = 0.f; kp[j] = 0.f; }
        #pragma unroll
        for (int u = 0; u < 2; ++u)
            #pragma unroll
            for (int v = 0; v < 2; ++v) {
                int rl = 2 * cr + u, ql = 2 * qp + v;
                half8 bf = *(const half8*)(&sM[(rl * 64 + ql) * CIP2 + chg * 8]);
                float2 p2 = *(const float2*)(pet + ((b * 256 + r0 + rl) * 256 + q0 + ql) * 16 + chg * 2);
                #pragma unroll
                for (int j = 0; j < 8; ++j) {
                    float bv = (float)bf[j];
                    dn[j] += bv;
                    kp[j] = fmaf((j < 4) ? p2.x : p2.y, bv, kp[j]);
                }
            }
        float* o = S2 + 2 * ((size_t)(((b * 128 + (r0 >> 1) + cr) * 128 + (q0 >> 1) + qp) * 64) + chg * 8);
        #pragma unroll
        for (int m = 0; m < 4; ++m)
            *(float4*)(o + 4 * m) = make_float4(dn[2*m], kp[2*m], dn[2*m+1], kp[2*m+1]);
    }
}

// ---------------- ratio: 4x4 cells -> 0.25 * kp/dn per patch ----------------
__global__ __launch_bounds__(256, 4)
void k_ratio(const float* __restrict__ S2, float* __restrict__ RATIO)
{
    int t = blockIdx.x * 256 + threadIdx.x;
    int cf = t & 63;
    int j  = (t >> 6) & 63;
    int i  = (t >> 12) & 63;
    int b  = t >> 18;
    float dn = 0.f, kp = 0.f;
    #pragma unroll
    for (int u = 0; u < 4; ++u) {
        int r2 = 2 * i - 1 + u;
        if ((unsigned)r2 >= 128u) continue;
        #pragma unroll
        for (int v = 0; v < 4; ++v) {
            int q2 = 2 * j - 1 + v;
            if ((unsigned)q2 >= 128u) continue;
            float2 s = *(const float2*)(S2 + 2 * (((b * 128 + r2) * 128 + q2) * 64 + cf));
            dn += s.x;
            kp += s.y;
        }
    }
    RATIO[t] = (dn == 0.f) ? 0.f : 0.25f * kp * __builtin_amdgcn_rcpf(dn);
}

// ---------------- out: U-table (i-phase sum) in LDS, dot with bf ----------------
__global__ __launch_bounds__(256, 4)
void k_out(const _Float16* __restrict__ BF, const float* __restrict__ RATIO,
           float* __restrict__ out)
{
    __shared__ __align__(16) float sU[64 * 68];   // [j][cf], row padded to 68
    const int tid = threadIdx.x;
    const int r = blockIdx.x & 255;
    const int b = blockIdx.x >> 8;

    const int i0 = (r <= 253) ? 2 * ((r + 2) >> 3)       : -1;
    const int i1 = (r >= 2)   ? 2 * ((r - 2) >> 3) + 1   : -1;

    for (int idx = tid; idx < 1024; idx += 256) {      // 1024 float4s
        int j = idx >> 4, c4 = idx & 15;
        float4 a = make_float4(0.f, 0.f, 0.f, 0.f);
        if (i0 >= 0) a = *(const float4*)&RATIO[(((b * 64 + i0) * 64 + j) << 6) + 4 * c4];
        float4 bb = make_float4(0.f, 0.f, 0.f, 0.f);
        if (i1 >= 0) bb = *(const float4*)&RATIO[(((b * 64 + i1) * 64 + j) << 6) + 4 * c4];
        *(float4*)&sU[j * 68 + 4 * c4] = make_float4(a.x + bb.x, a.y + bb.y, a.z + bb.z, a.w + bb.w);
    }
    __syncthreads();

    const int q = tid;
    const int j0 = (q <= 253) ? 2 * ((q + 2) >> 3)     : -1;
    const int j1 = (q >= 2)   ? 2 * ((q - 2) >> 3) + 1 : -1;

    const half8* bfp = (const half8*)(BF + ((size_t)(b * 256 + r) * 256 + q) * 64);
    float o[16];
    #pragma unroll
    for (int c = 0; c < 16; ++c) o[c] = 0.f;

    #pragma unroll
    for (int c2 = 0; c2 < 8; ++c2) {
        half8 bf8 = bfp[c2];
        float s0 = 0.f, s1 = 0.f;
        #pragma unroll
        for (int pj = 0; pj < 2; ++pj) {
            int jj = pj ? j1 : j0;
            if (jj < 0) continue;
            const float* up = &sU[jj * 68 + 8 * c2];
            s0 += (float)bf8[0] * up[0] + (float)bf8[1] * up[1]
                + (float)bf8[2] * up[2] + (float)bf8[3] * up[3];
            s1 += (float)bf8[4] * up[4] + (float)bf8[5] * up[5]
                + (float)bf8[6] * up[6] + (float)bf8[7] * up[7];
        }
        o[2 * c2]     = s0;
        o[2 * c2 + 1] = s1;
    }
    float* op = out + ((size_t)(b * 256 + r) * 256 + q) * 16;
    #pragma unroll
    for (int m = 0; m < 4; ++m)
        *(float4*)(op + 4 * m) = make_float4(o[4*m], o[4*m+1], o[4*m+2], o[4*m+3]);
}

extern "C" void kernel_launch(void* const* d_in, const int* in_sizes, int n_in,
                              void* d_out, int out_size, void* d_ws, size_t ws_size,
                              hipStream_t stream) {
    const float* mr  = (const float*)d_in[0];
    const float* pet = (const float*)d_in[1];
    const float* W1  = (const float*)d_in[2];
    const float* b1  = (const float*)d_in[3];
    const float* g1  = (const float*)d_in[4];
    const float* be1 = (const float*)d_in[5];
    const float* mu1 = (const float*)d_in[6];
    const float* v1  = (const float*)d_in[7];
    const float* W2  = (const float*)d_in[8];
    const float* b2  = (const float*)d_in[9];
    const float* g2  = (const float*)d_in[10];
    const float* be2 = (const float*)d_in[11];
    const float* mu2 = (const float*)d_in[12];
    const float* v2  = (const float*)d_in[13];

    // workspace layout (bytes):
    //   [0,        25165824)  A   f16 (3*256*256*64)
    //   [25165824, 50331648)  BF  f16 (3*256*256*64)
    //   [50331648, 75497472)  S2  fp32 (3*128*128*64*2)
    //   [75497472, 78643200)  RATIO fp32 (3*64*64*64)
    //   [78643200, 78663680)  W1F f16
    //   [78663680, 78737408)  W2F f16
    //   [78737408, 78738432)  ST  fp32
    char* ws = (char*)d_ws;
    _Float16* A     = (_Float16*)(ws);
    _Float16* BF    = (_Float16*)(ws + 25165824);
    float*    S2    = (float*)(ws + 50331648);
    float*    RATIO = (float*)(ws + 75497472);
    _Float16* W1F   = (_Float16*)(ws + 78643200);
    _Float16* W2F   = (_Float16*)(ws + 78663680);
    float*    ST    = (float*)(ws + 78737408);
    float*    out   = (float*)d_out;

    dim3 blk(256);
    k_prep<<<185, blk, 0, stream>>>(W1, W2, b1, g1, be1, mu1, v1,
                                    b2, g2, be2, mu2, v2, W1F, W2F, ST);
    k_conv1<<<dim3(256, 3), blk, 0, stream>>>(mr, W1F, ST, A);
    k_conv2<<<dim3(256, 3), blk, 0, stream>>>(A, W2F, ST, pet, BF, S2);
    k_ratio<<<3072, blk, 0, stream>>>(S2, RATIO);
    k_out<<<768, blk, 0, stream>>>(BF, RATIO, out);
}